// Round 1
// 1140.167 us; speedup vs baseline: 1.1261x; 1.1261x over previous
//
#include <hip/hip_runtime.h>

#define FL 12

// db6 analysis/synthesis filter banks (cross-correlation convention, matching
// lax.conv_general_dilated which does NOT flip kernels).
__constant__ float c_ana_lo[FL] = {
    0.11154074335008017f,  0.4946238903983854f,   0.7511339080215775f,   0.3152503517092432f,
   -0.22626469396516913f, -0.12976686756709563f,  0.09750160558707936f,  0.02752286553001629f,
   -0.031582039318031156f, 0.0005538422009938016f, 0.004777257511010651f, -0.00107730108499558f };
__constant__ float c_ana_hi[FL] = {
   -0.00107730108499558f, -0.004777257511010651f, 0.0005538422009938016f, 0.031582039318031156f,
    0.02752286553001629f, -0.09750160558707936f, -0.12976686756709563f,   0.22626469396516913f,
    0.3152503517092432f,  -0.7511339080215775f,   0.4946238903983854f,   -0.11154074335008017f };
__constant__ float c_syn_lo[FL] = {
   -0.00107730108499558f,  0.004777257511010651f, 0.0005538422009938016f, -0.031582039318031156f,
    0.02752286553001629f,  0.09750160558707936f, -0.12976686756709563f,  -0.22626469396516913f,
    0.3152503517092432f,   0.7511339080215775f,   0.4946238903983854f,    0.11154074335008017f };
__constant__ float c_syn_hi[FL] = {
   -0.11154074335008017f,  0.4946238903983854f,  -0.7511339080215775f,    0.3152503517092432f,
    0.22626469396516913f, -0.12976686756709563f, -0.09750160558707936f,   0.02752286553001629f,
    0.031582039318031156f, 0.0005538422009938016f, -0.004777257511010651f, -0.00107730108499558f };

// symmetric reflection (single reflection suffices: pad<=11 < min N=42)
__device__ __forceinline__ int symi(int i, int N) {
    i = (i < 0) ? (-1 - i) : i;
    i = (i >= N) ? (2 * N - 1 - i) : i;
    return i;
}

// ---------------- analysis along last axis (one block per row) -----------------
// Interior outputs (j0>=0 && j0+FL<=N, i.e. the vast majority) take a branch-free
// path: single LDS base address + 12 ds_read with immediate offsets + 12 v_fmac.
// symi's 4-VALU-op/tap + data-dependent addressing only runs on ~8 edge outputs.
template<bool BOTH>
__global__ __launch_bounds__(256) void afb_row(const float* __restrict__ in, float* __restrict__ lo,
                                               float* __restrict__ hi, int N, int Nout) {
    __shared__ float row[512];
    const int r = blockIdx.x;
    const float* src = in + (size_t)r * N;
    if ((N & 3) == 0) {
        // N%4==0 implies the row base is 16B aligned (r*N*4 % 16 == 0)
        const float4* s4 = (const float4*)src;
        float4* r4 = (float4*)row;
        for (int j = threadIdx.x; j < (N >> 2); j += 256) r4[j] = s4[j];
    } else {
        for (int j = threadIdx.x; j < N; j += 256) row[j] = src[j];
    }
    __syncthreads();
    const int padL = (2 * (Nout - 1) - N + FL) >> 1;
    for (int t = threadIdx.x; t < Nout; t += 256) {
        int j0 = 2 * t - padL;
        float alo = 0.f, ahi = 0.f;
        if (j0 >= 0 && j0 + FL <= N) {
            const float* w = &row[j0];
#pragma unroll
            for (int k = 0; k < FL; k++) {
                float v = w[k];
                alo += v * c_ana_lo[k];
                if (BOTH) ahi += v * c_ana_hi[k];
            }
        } else {
#pragma unroll
            for (int k = 0; k < FL; k++) {
                float v = row[symi(j0 + k, N)];
                alo += v * c_ana_lo[k];
                if (BOTH) ahi += v * c_ana_hi[k];
            }
        }
        lo[(size_t)r * Nout + t] = alo;
        if (BOTH) hi[(size_t)r * Nout + t] = ahi;
    }
}

// ---------------- analysis along rows (axis -2), thread per output elem --------
template<bool BOTH>
__global__ __launch_bounds__(256) void afb_col(const float* __restrict__ in, float* __restrict__ lo,
                                               float* __restrict__ hi, int Hin, int Hout, int W, int total) {
    int idx = blockIdx.x * 256 + threadIdx.x;
    if (idx >= total) return;
    int x = idx % W;
    int rw = idx / W;
    int t = rw % Hout;
    int img = rw / Hout;
    const float* src = in + (size_t)img * Hin * W + x;
    const int padL = (2 * (Hout - 1) - Hin + FL) >> 1;
    int j0 = 2 * t - padL;
    float alo = 0.f, ahi = 0.f;
    if (j0 >= 0 && j0 + FL <= Hin) {
        const float* p = src + (size_t)j0 * W;
#pragma unroll
        for (int k = 0; k < FL; k++) {
            float v = p[(size_t)k * W];
            alo += v * c_ana_lo[k];
            if (BOTH) ahi += v * c_ana_hi[k];
        }
    } else {
#pragma unroll
        for (int k = 0; k < FL; k++) {
            float v = src[(size_t)symi(j0 + k, Hin) * W];
            alo += v * c_ana_lo[k];
            if (BOTH) ahi += v * c_ana_hi[k];
        }
    }
    lo[idx] = alo;
    if (BOTH) hi[idx] = ahi;
}

// ---------------- synthesis along rows (axis -2), thread per output elem -------
// out[t,x] = sum_m lo[m,x]*syn_lo[2m-t+1] (+ hi[m,x]*syn_hi[2m-t+1])
// m in [t>>1, t>>1+5]; tau = 2d + 1-(t&1); no clamping needed for t in [0,2N-11].
// Parity-dependent filter taps are hoisted into registers via uniform scalar loads
// + one v_cndmask each (runtime-indexed __constant__ lowers to divergent loads).
template<bool TWO>
__global__ __launch_bounds__(256) void sfb_col(const float* __restrict__ lo, const float* __restrict__ hi,
                                               float* __restrict__ out, int rowStride, int imgStride,
                                               int W, int Hout, int total) {
    int idx = blockIdx.x * 256 + threadIdx.x;
    if (idx >= total) return;
    int x = idx % W;
    int rw = idx / W;
    int t = rw % Hout;
    int img = rw / Hout;
    const float* plo = lo + (size_t)img * imgStride + x;
    const float* phi = TWO ? hi + (size_t)img * imgStride + x : plo;
    int m0 = t >> 1;
    int odd = t & 1;  // tau0 = 1 - odd
    float wl[6], wh[6];
#pragma unroll
    for (int d = 0; d < 6; d++) {
        wl[d] = odd ? c_syn_lo[2 * d] : c_syn_lo[2 * d + 1];
        if (TWO) wh[d] = odd ? c_syn_hi[2 * d] : c_syn_hi[2 * d + 1];
    }
    float acc = 0.f;
#pragma unroll
    for (int d = 0; d < 6; d++) {
        int m = m0 + d;
        float a = plo[(size_t)m * rowStride] * wl[d];
        if (TWO) a += phi[(size_t)m * rowStride] * wh[d];
        acc += a;
    }
    out[idx] = acc;
}

// ---------------- synthesis along last axis (one block per row) ----------------
template<bool TWO>
__global__ __launch_bounds__(256) void sfb_row(const float* __restrict__ lo, const float* __restrict__ hi,
                                               float* __restrict__ out, int Nin, int Wout) {
    __shared__ float slo[136];
    __shared__ float shi[136];
    const int r = blockIdx.x;
    const float* pl = lo + (size_t)r * Nin;
    const float* ph = TWO ? hi + (size_t)r * Nin : pl;
    for (int j = threadIdx.x; j < Nin; j += 256) {
        slo[j] = pl[j];
        if (TWO) shi[j] = ph[j];
    }
    __syncthreads();
    for (int t = threadIdx.x; t < Wout; t += 256) {
        int m0 = t >> 1;
        int odd = t & 1;
        float wl[6], wh[6];
#pragma unroll
        for (int d = 0; d < 6; d++) {
            wl[d] = odd ? c_syn_lo[2 * d] : c_syn_lo[2 * d + 1];
            if (TWO) wh[d] = odd ? c_syn_hi[2 * d] : c_syn_hi[2 * d + 1];
        }
        float acc = 0.f;
#pragma unroll
        for (int d = 0; d < 6; d++) {
            acc += slo[m0 + d] * wl[d];
            if (TWO) acc += shi[m0 + d] * wh[d];
        }
        out[(size_t)r * Wout + t] = acc;
    }
}

// ---------------- per-pixel channel mix, delta form, in place ------------------
// Delta[b,o,p] = sum_i band[b,i,p]*w[i,o,(c),p] - band[b,o,p]
__global__ __launch_bounds__(256) void mix_bands(float* __restrict__ yl, float* __restrict__ lh,
                                                 float* __restrict__ hl, float* __restrict__ hh,
                                                 const float* __restrict__ w_yl, const float* __restrict__ w_yh) {
    const int P = 1764;  // 42*42
    int blk = blockIdx.x;
    int tile = blk % 221;
    int b = (blk / 221) % 8;
    int c = blk / (221 * 8);
    float* band = (c == 0) ? yl : (c == 1) ? lh : (c == 2) ? hl : hh;
    int p0 = tile * 8;
    __shared__ float sb[256];
    int i = threadIdx.x >> 3;
    int dp = threadIdx.x & 7;
    int p = p0 + dp;
    sb[threadIdx.x] = (p < P) ? band[(size_t)(b * 32 + i) * P + p] : 0.f;
    __syncthreads();
    int o = i;
    if (p < P) {
        float acc = 0.f;
        if (c == 0) {
#pragma unroll 4
            for (int ii = 0; ii < 32; ii++)
                acc += sb[(ii << 3) | dp] * w_yl[(size_t)(ii * 32 + o) * P + p];
        } else {
            const float* wb = w_yh + (size_t)(c - 1) * P;
#pragma unroll 4
            for (int ii = 0; ii < 32; ii++)
                acc += sb[(ii << 3) | dp] * wb[(size_t)(ii * 32 + o) * 3 * P + p];
        }
        acc -= sb[(o << 3) | dp];
        band[(size_t)(b * 32 + o) * P + p] = acc;
    }
}

// ---------------- fused final level: col-synth row + row-synth + add x ---------
// u2: (256,262,262), use [:261,:261]. One block per output row (img,y).
__global__ __launch_bounds__(256) void final_fuse(const float* __restrict__ u2, const float* __restrict__ x,
                                                  float* __restrict__ out) {
    __shared__ float t1row[261];
    int img = blockIdx.x >> 9;
    int y = blockIdx.x & 511;
    const float* pu = u2 + (size_t)img * 262 * 262;
    int m0y = y >> 1;
    int oddy = y & 1;
    float wy[6];
#pragma unroll
    for (int d = 0; d < 6; d++)
        wy[d] = oddy ? c_syn_lo[2 * d] : c_syn_lo[2 * d + 1];
    for (int xc = threadIdx.x; xc < 261; xc += 256) {
        float acc = 0.f;
#pragma unroll
        for (int d = 0; d < 6; d++)
            acc += pu[(size_t)(m0y + d) * 262 + xc] * wy[d];
        t1row[xc] = acc;
    }
    __syncthreads();
    const float* px = x + ((size_t)img * 512 + y) * 512;
    float* po = out + ((size_t)img * 512 + y) * 512;
    for (int t = threadIdx.x; t < 512; t += 256) {
        int m0 = t >> 1;
        int odd = t & 1;
        float wl[6];
#pragma unroll
        for (int d = 0; d < 6; d++)
            wl[d] = odd ? c_syn_lo[2 * d] : c_syn_lo[2 * d + 1];
        float acc = px[t];
#pragma unroll
        for (int d = 0; d < 6; d++)
            acc += t1row[m0 + d] * wl[d];
        po[t] = acc;
    }
}

extern "C" void kernel_launch(void* const* d_in, const int* in_sizes, int n_in,
                              void* d_out, int out_size, void* d_ws, size_t ws_size,
                              hipStream_t stream) {
    (void)in_sizes; (void)n_in; (void)out_size; (void)ws_size;
    const float* x = (const float*)d_in[0];      // (8,32,512,512)
    const float* w_yl = (const float*)d_in[1];   // (32,32,42,42)
    const float* w_yh = (const float*)d_in[2];   // (32,32,3,42,42)
    float* out = (float*)d_out;
    float* ws = (float*)d_ws;

    // Scratch in d_out (dead before the final write):
    float* loW1 = out;             // (256*512, 261)  = 34,209,792 floats
    float* ll1 = out + 34209792;   // (256, 261, 261) = 17,438,976 floats

    // Scratch in d_ws (float offsets); slots are reused fwd/bwd:
    float* u2  = ws;               // (256,262,262)
    float* slC = ws + 17572864;    // fwd loW2 (256*261,136) / syn t2 (256,262,136)
    float* slD = slC + 9121792;    // fwd ll2 (256,136,136)  / syn u3
    float* slE = slD + 4734976;    // fwd loW3 (256*136,73)  / syn t3
    float* slF = slE + 2541568;    // fwd ll3 (256,73,73)    / syn dLL (256,74,74)
    float* g1  = slF + 1401856;    // lo4w (256,73,42) / dlo' (256,74,42)
    float* g2  = g1 + 795648;      // hi4w / dhi'
    float* g3  = g2 + 795648;      // yl   (256,42,42) -> delta in place
    float* g4  = g3 + 451584;      // lh
    float* g5  = g4 + 451584;      // hl
    float* g6  = g5 + 451584;      // hh
    // total ws: 155,082,752 bytes

    dim3 B(256);
    // ---- forward lowpass chain (512 -> 261 -> 136 -> 73), full split at level 4
    afb_row<false><<<256 * 512, B, 0, stream>>>(x, loW1, nullptr, 512, 261);
    { int tot = 256 * 261 * 261; afb_col<false><<<(tot + 255) / 256, B, 0, stream>>>(loW1, ll1, nullptr, 512, 261, 261, tot); }
    afb_row<false><<<256 * 261, B, 0, stream>>>(ll1, slC, nullptr, 261, 136);
    { int tot = 256 * 136 * 136; afb_col<false><<<(tot + 255) / 256, B, 0, stream>>>(slC, slD, nullptr, 261, 136, 136, tot); }
    afb_row<false><<<256 * 136, B, 0, stream>>>(slD, slE, nullptr, 136, 73);
    { int tot = 256 * 73 * 73; afb_col<false><<<(tot + 255) / 256, B, 0, stream>>>(slE, slF, nullptr, 136, 73, 73, tot); }
    afb_row<true><<<256 * 73, B, 0, stream>>>(slF, g1, g2, 73, 42);
    { int tot = 256 * 42 * 42; afb_col<true><<<(tot + 255) / 256, B, 0, stream>>>(g1, g3, g4, 73, 42, 42, tot); }
    { int tot = 256 * 42 * 42; afb_col<true><<<(tot + 255) / 256, B, 0, stream>>>(g2, g5, g6, 73, 42, 42, tot); }

    // ---- channel mix (delta form, in place on g3..g6)
    mix_bands<<<4 * 8 * 221, B, 0, stream>>>(g3, g4, g5, g6, w_yl, w_yh);

    // ---- synthesis of the delta (all level-1..3 high bands are zero)
    { int tot = 256 * 74 * 42; sfb_col<true><<<(tot + 255) / 256, B, 0, stream>>>(g3, g4, g1, 42, 42 * 42, 42, 74, tot); }
    { int tot = 256 * 74 * 42; sfb_col<true><<<(tot + 255) / 256, B, 0, stream>>>(g5, g6, g2, 42, 42 * 42, 42, 74, tot); }
    sfb_row<true><<<256 * 74, B, 0, stream>>>(g1, g2, slF, 42, 74);                       // dLL3full (74x74)
    { int tot = 256 * 136 * 73; sfb_col<false><<<(tot + 255) / 256, B, 0, stream>>>(slF, nullptr, slE, 74, 74 * 74, 73, 136, tot); } // crop 73
    sfb_row<false><<<256 * 136, B, 0, stream>>>(slE, nullptr, slD, 73, 136);              // u3 (136,136)
    { int tot = 256 * 262 * 136; sfb_col<false><<<(tot + 255) / 256, B, 0, stream>>>(slD, nullptr, slC, 136, 136 * 136, 136, 262, tot); }
    sfb_row<false><<<256 * 262, B, 0, stream>>>(slC, nullptr, u2, 136, 262);              // u2 (262,262), crop to 261 at read

    // ---- fused final level + add x
    final_fuse<<<256 * 512, B, 0, stream>>>(u2, x, out);
}

// Round 2
// 1020.174 us; speedup vs baseline: 1.2586x; 1.1176x over previous
//
#include <hip/hip_runtime.h>

#define FL 12

// db6 analysis/synthesis filter banks (cross-correlation convention, matching
// lax.conv_general_dilated which does NOT flip kernels).
__constant__ float c_ana_lo[FL] = {
    0.11154074335008017f,  0.4946238903983854f,   0.7511339080215775f,   0.3152503517092432f,
   -0.22626469396516913f, -0.12976686756709563f,  0.09750160558707936f,  0.02752286553001629f,
   -0.031582039318031156f, 0.0005538422009938016f, 0.004777257511010651f, -0.00107730108499558f };
__constant__ float c_ana_hi[FL] = {
   -0.00107730108499558f, -0.004777257511010651f, 0.0005538422009938016f, 0.031582039318031156f,
    0.02752286553001629f, -0.09750160558707936f, -0.12976686756709563f,   0.22626469396516913f,
    0.3152503517092432f,  -0.7511339080215775f,   0.4946238903983854f,   -0.11154074335008017f };
__constant__ float c_syn_lo[FL] = {
   -0.00107730108499558f,  0.004777257511010651f, 0.0005538422009938016f, -0.031582039318031156f,
    0.02752286553001629f,  0.09750160558707936f, -0.12976686756709563f,  -0.22626469396516913f,
    0.3152503517092432f,   0.7511339080215775f,   0.4946238903983854f,    0.11154074335008017f };
__constant__ float c_syn_hi[FL] = {
   -0.11154074335008017f,  0.4946238903983854f,  -0.7511339080215775f,    0.3152503517092432f,
    0.22626469396516913f, -0.12976686756709563f, -0.09750160558707936f,   0.02752286553001629f,
    0.031582039318031156f, 0.0005538422009938016f, -0.004777257511010651f, -0.00107730108499558f };

// symmetric reflection (single reflection suffices: pad<=11 < min N=42)
__device__ __forceinline__ int symi(int i, int N) {
    i = (i < 0) ? (-1 - i) : i;
    i = (i >= N) ? (2 * N - 1 - i) : i;
    return i;
}

// ---------------- analysis along last axis (one block per row) -----------------
// Interior outputs take a branch-free path: single LDS base + 12 ds_read with
// immediate offsets + 12 v_fmac. symi only runs on ~8 edge outputs per row.
template<bool BOTH>
__global__ __launch_bounds__(256) void afb_row(const float* __restrict__ in, float* __restrict__ lo,
                                               float* __restrict__ hi, int N, int Nout) {
    __shared__ float row[512];
    const int r = blockIdx.x;
    const float* src = in + (size_t)r * N;
    if ((N & 3) == 0) {
        const float4* s4 = (const float4*)src;
        float4* r4 = (float4*)row;
        for (int j = threadIdx.x; j < (N >> 2); j += 256) r4[j] = s4[j];
    } else {
        for (int j = threadIdx.x; j < N; j += 256) row[j] = src[j];
    }
    __syncthreads();
    const int padL = (2 * (Nout - 1) - N + FL) >> 1;
    for (int t = threadIdx.x; t < Nout; t += 256) {
        int j0 = 2 * t - padL;
        float alo = 0.f, ahi = 0.f;
        if (j0 >= 0 && j0 + FL <= N) {
            const float* w = &row[j0];
#pragma unroll
            for (int k = 0; k < FL; k++) {
                float v = w[k];
                alo += v * c_ana_lo[k];
                if (BOTH) ahi += v * c_ana_hi[k];
            }
        } else {
#pragma unroll
            for (int k = 0; k < FL; k++) {
                float v = row[symi(j0 + k, N)];
                alo += v * c_ana_lo[k];
                if (BOTH) ahi += v * c_ana_hi[k];
            }
        }
        lo[(size_t)r * Nout + t] = alo;
        if (BOTH) hi[(size_t)r * Nout + t] = ahi;
    }
}

// ---------------- analysis along rows (axis -2), thread per output elem --------
template<bool BOTH>
__global__ __launch_bounds__(256) void afb_col(const float* __restrict__ in, float* __restrict__ lo,
                                               float* __restrict__ hi, int Hin, int Hout, int W, int total) {
    int idx = blockIdx.x * 256 + threadIdx.x;
    if (idx >= total) return;
    int x = idx % W;
    int rw = idx / W;
    int t = rw % Hout;
    int img = rw / Hout;
    const float* src = in + (size_t)img * Hin * W + x;
    const int padL = (2 * (Hout - 1) - Hin + FL) >> 1;
    int j0 = 2 * t - padL;
    float alo = 0.f, ahi = 0.f;
    if (j0 >= 0 && j0 + FL <= Hin) {
        const float* p = src + (size_t)j0 * W;
#pragma unroll
        for (int k = 0; k < FL; k++) {
            float v = p[(size_t)k * W];
            alo += v * c_ana_lo[k];
            if (BOTH) ahi += v * c_ana_hi[k];
        }
    } else {
#pragma unroll
        for (int k = 0; k < FL; k++) {
            float v = src[(size_t)symi(j0 + k, Hin) * W];
            alo += v * c_ana_lo[k];
            if (BOTH) ahi += v * c_ana_hi[k];
        }
    }
    lo[idx] = alo;
    if (BOTH) hi[idx] = ahi;
}

// ---------------- synthesis along rows (axis -2), thread per output elem -------
template<bool TWO>
__global__ __launch_bounds__(256) void sfb_col(const float* __restrict__ lo, const float* __restrict__ hi,
                                               float* __restrict__ out, int rowStride, int imgStride,
                                               int W, int Hout, int total) {
    int idx = blockIdx.x * 256 + threadIdx.x;
    if (idx >= total) return;
    int x = idx % W;
    int rw = idx / W;
    int t = rw % Hout;
    int img = rw / Hout;
    const float* plo = lo + (size_t)img * imgStride + x;
    const float* phi = TWO ? hi + (size_t)img * imgStride + x : plo;
    int m0 = t >> 1;
    int odd = t & 1;
    float wl[6], wh[6];
#pragma unroll
    for (int d = 0; d < 6; d++) {
        wl[d] = odd ? c_syn_lo[2 * d] : c_syn_lo[2 * d + 1];
        if (TWO) wh[d] = odd ? c_syn_hi[2 * d] : c_syn_hi[2 * d + 1];
    }
    float acc = 0.f;
#pragma unroll
    for (int d = 0; d < 6; d++) {
        int m = m0 + d;
        float a = plo[(size_t)m * rowStride] * wl[d];
        if (TWO) a += phi[(size_t)m * rowStride] * wh[d];
        acc += a;
    }
    out[idx] = acc;
}

// ---------------- synthesis along last axis (one block per row) ----------------
template<bool TWO>
__global__ __launch_bounds__(256) void sfb_row(const float* __restrict__ lo, const float* __restrict__ hi,
                                               float* __restrict__ out, int Nin, int Wout) {
    __shared__ float slo[136];
    __shared__ float shi[136];
    const int r = blockIdx.x;
    const float* pl = lo + (size_t)r * Nin;
    const float* ph = TWO ? hi + (size_t)r * Nin : pl;
    for (int j = threadIdx.x; j < Nin; j += 256) {
        slo[j] = pl[j];
        if (TWO) shi[j] = ph[j];
    }
    __syncthreads();
    for (int t = threadIdx.x; t < Wout; t += 256) {
        int m0 = t >> 1;
        int odd = t & 1;
        float wl[6], wh[6];
#pragma unroll
        for (int d = 0; d < 6; d++) {
            wl[d] = odd ? c_syn_lo[2 * d] : c_syn_lo[2 * d + 1];
            if (TWO) wh[d] = odd ? c_syn_hi[2 * d] : c_syn_hi[2 * d + 1];
        }
        float acc = 0.f;
#pragma unroll
        for (int d = 0; d < 6; d++) {
            acc += slo[m0 + d] * wl[d];
            if (TWO) acc += shi[m0 + d] * wh[d];
        }
        out[(size_t)r * Wout + t] = acc;
    }
}

// ---------------- per-pixel channel mix, delta form, in place ------------------
__global__ __launch_bounds__(256) void mix_bands(float* __restrict__ yl, float* __restrict__ lh,
                                                 float* __restrict__ hl, float* __restrict__ hh,
                                                 const float* __restrict__ w_yl, const float* __restrict__ w_yh) {
    const int P = 1764;  // 42*42
    int blk = blockIdx.x;
    int tile = blk % 221;
    int b = (blk / 221) % 8;
    int c = blk / (221 * 8);
    float* band = (c == 0) ? yl : (c == 1) ? lh : (c == 2) ? hl : hh;
    int p0 = tile * 8;
    __shared__ float sb[256];
    int i = threadIdx.x >> 3;
    int dp = threadIdx.x & 7;
    int p = p0 + dp;
    sb[threadIdx.x] = (p < P) ? band[(size_t)(b * 32 + i) * P + p] : 0.f;
    __syncthreads();
    int o = i;
    if (p < P) {
        float acc = 0.f;
        if (c == 0) {
#pragma unroll 4
            for (int ii = 0; ii < 32; ii++)
                acc += sb[(ii << 3) | dp] * w_yl[(size_t)(ii * 32 + o) * P + p];
        } else {
            const float* wb = w_yh + (size_t)(c - 1) * P;
#pragma unroll 4
            for (int ii = 0; ii < 32; ii++)
                acc += sb[(ii << 3) | dp] * wb[(size_t)(ii * 32 + o) * 3 * P + p];
        }
        acc -= sb[(o << 3) | dp];
        band[(size_t)(b * 32 + o) * P + p] = acc;
    }
}

// ---------------- fused final: row-synth(slC)->u2 rows + col-synth + row-synth + add x
// Block = (img, q): output rows y = 8q..8q+7. Needs u2 rows 4q..4q+8 (9 rows),
// each recomputed in LDS from slC (256,262,136) — kills the u2 HBM round trip.
// x preloaded into 16 regs at kernel top so HBM latency hides under phases 0-1.
__global__ __launch_bounds__(256) void final_fuse(const float* __restrict__ slC, const float* __restrict__ x,
                                                  float* __restrict__ out) {
    __shared__ float u2t[9][262];  // u2 rows mBase..mBase+8
    __shared__ float t1[8][262];   // col-synthesized rows for y0..y0+7
    int img = blockIdx.x >> 6;
    int q = blockIdx.x & 63;
    int y0 = q << 3;
    int mBase = q << 2;
    const float* pc = slC + (size_t)img * 262 * 136;
    const float* px = x + ((size_t)img * 512 + y0) * 512;
    float* po = out + ((size_t)img * 512 + y0) * 512;

    // preload x tile (independent of everything; covers latency across barriers)
    float xv[16];
#pragma unroll
    for (int yy = 0; yy < 8; yy++) {
        xv[2 * yy]     = px[(size_t)yy * 512 + threadIdx.x];
        xv[2 * yy + 1] = px[(size_t)yy * 512 + threadIdx.x + 256];
    }

    // phase 0: u2t[mp][xc] = sum_d slC[img][mBase+mp][(xc>>1)+d] * syn_lo[parity(xc)]
    for (int e = threadIdx.x; e < 9 * 262; e += 256) {
        int mp = e / 262;
        int xc = e - mp * 262;
        const float* pr = pc + (size_t)(mBase + mp) * 136 + (xc >> 1);
        int odd = xc & 1;
        float acc = 0.f;
#pragma unroll
        for (int d = 0; d < 6; d++) {
            float w = odd ? c_syn_lo[2 * d] : c_syn_lo[2 * d + 1];
            acc += pr[d] * w;
        }
        u2t[0][e] = acc;
    }
    __syncthreads();

    // phase 1: t1[yy][xc] = sum_d u2t[(yy>>1)+d][xc] * syn_lo[parity(yy)]
    for (int e = threadIdx.x; e < 8 * 262; e += 256) {
        int yy = e / 262;
        int xc = e - yy * 262;
        int m0 = yy >> 1;
        int odd = yy & 1;  // y0 is even, so parity(y) == parity(yy)
        float acc = 0.f;
#pragma unroll
        for (int d = 0; d < 6; d++) {
            float w = odd ? c_syn_lo[2 * d] : c_syn_lo[2 * d + 1];
            acc += u2t[m0 + d][xc] * w;
        }
        t1[0][e] = acc;
    }
    __syncthreads();

    // phase 2: out[y][t] = x[y][t] + sum_d t1[yy][(t>>1)+d] * syn_lo[parity(t)]
    int odd = threadIdx.x & 1;  // t = tid and tid+256 share parity
    float wl[6];
#pragma unroll
    for (int d = 0; d < 6; d++) wl[d] = odd ? c_syn_lo[2 * d] : c_syn_lo[2 * d + 1];
#pragma unroll
    for (int yy = 0; yy < 8; yy++) {
#pragma unroll
        for (int h = 0; h < 2; h++) {
            int t = threadIdx.x + (h << 8);
            int m0 = t >> 1;
            float acc = xv[2 * yy + h];
#pragma unroll
            for (int d = 0; d < 6; d++) acc += t1[yy][m0 + d] * wl[d];
            po[(size_t)yy * 512 + t] = acc;
        }
    }
}

extern "C" void kernel_launch(void* const* d_in, const int* in_sizes, int n_in,
                              void* d_out, int out_size, void* d_ws, size_t ws_size,
                              hipStream_t stream) {
    (void)in_sizes; (void)n_in; (void)out_size; (void)ws_size;
    const float* x = (const float*)d_in[0];      // (8,32,512,512)
    const float* w_yl = (const float*)d_in[1];   // (32,32,42,42)
    const float* w_yh = (const float*)d_in[2];   // (32,32,3,42,42)
    float* out = (float*)d_out;
    float* ws = (float*)d_ws;

    // Scratch in d_out (dead before the final write):
    float* loW1 = out;             // (256*512, 261)  = 34,209,792 floats
    float* ll1 = out + 34209792;   // (256, 261, 261) = 17,438,976 floats

    // Scratch in d_ws (float offsets); slots are reused fwd/bwd:
    // (ws slot 0, formerly u2, now unused — final stage reads slC directly)
    float* slC = ws + 17572864;    // fwd loW2 (256*261,136) / syn t2 (256,262,136)
    float* slD = slC + 9121792;    // fwd ll2 (256,136,136)  / syn u3
    float* slE = slD + 4734976;    // fwd loW3 (256*136,73)  / syn t3
    float* slF = slE + 2541568;    // fwd ll3 (256,73,73)    / syn dLL (256,74,74)
    float* g1  = slF + 1401856;    // lo4w (256,73,42) / dlo' (256,74,42)
    float* g2  = g1 + 795648;      // hi4w / dhi'
    float* g3  = g2 + 795648;      // yl   (256,42,42) -> delta in place
    float* g4  = g3 + 451584;      // lh
    float* g5  = g4 + 451584;      // hl
    float* g6  = g5 + 451584;      // hh

    dim3 B(256);
    // ---- forward lowpass chain (512 -> 261 -> 136 -> 73), full split at level 4
    afb_row<false><<<256 * 512, B, 0, stream>>>(x, loW1, nullptr, 512, 261);
    { int tot = 256 * 261 * 261; afb_col<false><<<(tot + 255) / 256, B, 0, stream>>>(loW1, ll1, nullptr, 512, 261, 261, tot); }
    afb_row<false><<<256 * 261, B, 0, stream>>>(ll1, slC, nullptr, 261, 136);
    { int tot = 256 * 136 * 136; afb_col<false><<<(tot + 255) / 256, B, 0, stream>>>(slC, slD, nullptr, 261, 136, 136, tot); }
    afb_row<false><<<256 * 136, B, 0, stream>>>(slD, slE, nullptr, 136, 73);
    { int tot = 256 * 73 * 73; afb_col<false><<<(tot + 255) / 256, B, 0, stream>>>(slE, slF, nullptr, 136, 73, 73, tot); }
    afb_row<true><<<256 * 73, B, 0, stream>>>(slF, g1, g2, 73, 42);
    { int tot = 256 * 42 * 42; afb_col<true><<<(tot + 255) / 256, B, 0, stream>>>(g1, g3, g4, 73, 42, 42, tot); }
    { int tot = 256 * 42 * 42; afb_col<true><<<(tot + 255) / 256, B, 0, stream>>>(g2, g5, g6, 73, 42, 42, tot); }

    // ---- channel mix (delta form, in place on g3..g6)
    mix_bands<<<4 * 8 * 221, B, 0, stream>>>(g3, g4, g5, g6, w_yl, w_yh);

    // ---- synthesis of the delta (all level-1..3 high bands are zero)
    { int tot = 256 * 74 * 42; sfb_col<true><<<(tot + 255) / 256, B, 0, stream>>>(g3, g4, g1, 42, 42 * 42, 42, 74, tot); }
    { int tot = 256 * 74 * 42; sfb_col<true><<<(tot + 255) / 256, B, 0, stream>>>(g5, g6, g2, 42, 42 * 42, 42, 74, tot); }
    sfb_row<true><<<256 * 74, B, 0, stream>>>(g1, g2, slF, 42, 74);                       // dLL3full (74x74)
    { int tot = 256 * 136 * 73; sfb_col<false><<<(tot + 255) / 256, B, 0, stream>>>(slF, nullptr, slE, 74, 74 * 74, 73, 136, tot); } // crop 73
    sfb_row<false><<<256 * 136, B, 0, stream>>>(slE, nullptr, slD, 73, 136);              // u3 (136,136)
    { int tot = 256 * 262 * 136; sfb_col<false><<<(tot + 255) / 256, B, 0, stream>>>(slD, nullptr, slC, 136, 136 * 136, 136, 262, tot); }

    // ---- fused final level (recomputes u2 rows from slC in LDS) + add x
    final_fuse<<<256 * 64, B, 0, stream>>>(slC, x, out);
}